// Round 2
// baseline (2230.544 us; speedup 1.0000x reference)
//
#include <hip/hip_runtime.h>

// CoAttention: B=64, H=768, T=384. out (64,384,2304) fp32.
// ws layout (bytes), with aliasing (Qhi/Qlo dead after gemm2; reused for AQt/ADt):
//   Qhi bf16 (64,384,768)  @ 0           37,748,736   later: AQt bf16 (64,384,384) @ 0
//   Qlo bf16 (64,384,768)  @ 37748736    37,748,736   later: ADt bf16 (64,384,384) @ 37748736
//   M4  bf16 (64,1536,384) @ 75497472    75,497,472   rows 0..767 Qact^T, 768..1535 C_Q
//   Dt  bf16 (64,768,384)  @ 150994944   37,748,736
//   L   f32  (64,384,384)  @ 188743680   37,748,736
// total 226,492,416 bytes

typedef __bf16 bf16x8 __attribute__((ext_vector_type(8)));
typedef float  f32x4  __attribute__((ext_vector_type(4)));

#define BB 64
#define HH 768
#define TT 384

// split fp32 -> hi/lo bf16 (hi+lo reproduces fp32 to ~2^-17 relative)
__device__ inline void split8(const float* __restrict__ p, bf16x8& hi, bf16x8& lo) {
    float4 f0 = *(const float4*)p;
    float4 f1 = *(const float4*)(p + 4);
    float f[8] = {f0.x, f0.y, f0.z, f0.w, f1.x, f1.y, f1.z, f1.w};
#pragma unroll
    for (int i = 0; i < 8; i++) {
        __bf16 h = (__bf16)f[i];
        hi[i] = h;
        lo[i] = (__bf16)(f[i] - (float)h);
    }
}

// ---- prep: Dt[b][h][s] = bf16(D[b][s][h]);  out[b][s][1536+h] = D[b][s][h] ----
__global__ void prep_kernel(const float* __restrict__ x, __bf16* __restrict__ Dt,
                            float* __restrict__ out) {
    __shared__ float tile[32][33];
    int b = blockIdx.z;
    int h0 = blockIdx.x * 32, s0 = blockIdx.y * 32;
    int tx = threadIdx.x, ty = threadIdx.y;
    const float* src = x + ((size_t)b * HH + TT) * HH;  // D rows
    float* outb = out + (size_t)b * TT * 2304;
#pragma unroll
    for (int j = 0; j < 4; j++) {
        int s = s0 + ty + 8 * j, h = h0 + tx;
        float v = src[(size_t)s * HH + h];
        tile[ty + 8 * j][tx] = v;
        outb[(size_t)s * 2304 + 1536 + h] = v;
    }
    __syncthreads();
    __bf16* Dtb = Dt + (size_t)b * HH * TT;
#pragma unroll
    for (int j = 0; j < 4; j++) {
        int h = h0 + ty + 8 * j, s = s0 + tx;
        Dtb[(size_t)h * TT + s] = (__bf16)tile[tx][ty + 8 * j];
    }
}

// ---- gemm1 (split precision): pre = x_Q @ W^T + b; Qact = tanh(pre)
//      stores Qhi/Qlo (hi/lo bf16 planes) and M4[o][t] = bf16(Qact[t][o]) ----
__global__ void gemm1_kernel(const float* __restrict__ x, const float* __restrict__ W,
                             const float* __restrict__ bias, __bf16* __restrict__ Qhi,
                             __bf16* __restrict__ Qlo, __bf16* __restrict__ M4) {
    int b = blockIdx.z;
    int m0 = blockIdx.y * 16, n0 = blockIdx.x * 16;
    int lane = threadIdx.x;
    int mr = lane & 15, kq = (lane >> 4) * 8;
    const float* A = x + (size_t)b * HH * HH;  // Q rows t<384
    f32x4 acc = {0.f, 0.f, 0.f, 0.f};
    const float* pa = A + (size_t)(m0 + mr) * HH + kq;
    const float* pb = W + (size_t)(n0 + mr) * HH + kq;
    for (int k0 = 0; k0 < HH; k0 += 32) {
        bf16x8 ah, al, bh, bl;
        split8(pa + k0, ah, al);
        split8(pb + k0, bh, bl);
        acc = __builtin_amdgcn_mfma_f32_16x16x32_bf16(ah, bh, acc, 0, 0, 0);
        acc = __builtin_amdgcn_mfma_f32_16x16x32_bf16(ah, bl, acc, 0, 0, 0);
        acc = __builtin_amdgcn_mfma_f32_16x16x32_bf16(al, bh, acc, 0, 0, 0);
    }
    int col = n0 + (lane & 15);
    int row0 = m0 + (lane >> 4) * 4;
    float bv = bias[col];
    __bf16* Qh = Qhi + (size_t)b * TT * HH;
    __bf16* Ql = Qlo + (size_t)b * TT * HH;
    __bf16* Mb = M4 + (size_t)b * 1536 * TT;
#pragma unroll
    for (int r = 0; r < 4; r++) {
        float v = tanhf(acc[r] + bv);
        __bf16 qh = (__bf16)v;
        __bf16 ql = (__bf16)(v - (float)qh);
        Qh[(size_t)(row0 + r) * HH + col] = qh;
        Ql[(size_t)(row0 + r) * HH + col] = ql;
        Mb[(size_t)col * TT + row0 + r] = qh;
    }
}

// ---- gemm2 (split precision): L[t][s] = sum_h Qact[t][h]*D[s][h] ----
__global__ void gemm2_kernel(const __bf16* __restrict__ Qhi, const __bf16* __restrict__ Qlo,
                             const float* __restrict__ x, float* __restrict__ L) {
    int b = blockIdx.z;
    int m0 = blockIdx.y * 16, n0 = blockIdx.x * 16;
    int lane = threadIdx.x;
    int mr = lane & 15, kq = (lane >> 4) * 8;
    const __bf16* Ah = Qhi + (size_t)b * TT * HH + (size_t)(m0 + mr) * HH + kq;
    const __bf16* Al = Qlo + (size_t)b * TT * HH + (size_t)(m0 + mr) * HH + kq;
    const float* Bd = x + ((size_t)b * HH + TT) * HH + (size_t)(n0 + mr) * HH + kq;
    f32x4 acc = {0.f, 0.f, 0.f, 0.f};
    for (int k0 = 0; k0 < HH; k0 += 32) {
        bf16x8 ah = *(const bf16x8*)(Ah + k0);
        bf16x8 al = *(const bf16x8*)(Al + k0);
        bf16x8 bh, bl;
        split8(Bd + k0, bh, bl);
        acc = __builtin_amdgcn_mfma_f32_16x16x32_bf16(ah, bh, acc, 0, 0, 0);
        acc = __builtin_amdgcn_mfma_f32_16x16x32_bf16(ah, bl, acc, 0, 0, 0);
        acc = __builtin_amdgcn_mfma_f32_16x16x32_bf16(al, bh, acc, 0, 0, 0);
    }
    float* Lb = L + (size_t)b * TT * TT;
    int col = n0 + (lane & 15);
    int row0 = m0 + (lane >> 4) * 4;
#pragma unroll
    for (int r = 0; r < 4; r++) Lb[(size_t)(row0 + r) * TT + col] = acc[r];
}

// ---- softmax over t (column) of L -> AQt[t][s] ----
__global__ void softmax_col_kernel(const float* __restrict__ L, __bf16* __restrict__ AQt) {
    int s = blockIdx.x, b = blockIdx.y;
    int tid = threadIdx.x;  // 128
    const float* Lb = L + (size_t)b * TT * TT;
    float v0 = Lb[(size_t)tid * TT + s];
    float v1 = Lb[(size_t)(tid + 128) * TT + s];
    float v2 = Lb[(size_t)(tid + 256) * TT + s];
    __shared__ float red[128];
    red[tid] = fmaxf(fmaxf(v0, v1), v2);
    __syncthreads();
    for (int off = 64; off > 0; off >>= 1) {
        if (tid < off) red[tid] = fmaxf(red[tid], red[tid + off]);
        __syncthreads();
    }
    float mx = red[0];
    __syncthreads();
    float e0 = __expf(v0 - mx), e1 = __expf(v1 - mx), e2 = __expf(v2 - mx);
    red[tid] = e0 + e1 + e2;
    __syncthreads();
    for (int off = 64; off > 0; off >>= 1) {
        if (tid < off) red[tid] += red[tid + off];
        __syncthreads();
    }
    float inv = 1.0f / red[0];
    __bf16* Ab = AQt + (size_t)b * TT * TT;
    Ab[(size_t)tid * TT + s] = (__bf16)(e0 * inv);
    Ab[(size_t)(tid + 128) * TT + s] = (__bf16)(e1 * inv);
    Ab[(size_t)(tid + 256) * TT + s] = (__bf16)(e2 * inv);
}

// ---- softmax over s (row) of L -> ADt[s][t] (transposed store) ----
__global__ void softmax_row_kernel(const float* __restrict__ L, __bf16* __restrict__ ADt) {
    int t = blockIdx.x, b = blockIdx.y;
    int tid = threadIdx.x;  // 128
    const float* Lb = L + (size_t)b * TT * TT + (size_t)t * TT;
    float v0 = Lb[tid], v1 = Lb[tid + 128], v2 = Lb[tid + 256];
    __shared__ float red[128];
    red[tid] = fmaxf(fmaxf(v0, v1), v2);
    __syncthreads();
    for (int off = 64; off > 0; off >>= 1) {
        if (tid < off) red[tid] = fmaxf(red[tid], red[tid + off]);
        __syncthreads();
    }
    float mx = red[0];
    __syncthreads();
    float e0 = __expf(v0 - mx), e1 = __expf(v1 - mx), e2 = __expf(v2 - mx);
    red[tid] = e0 + e1 + e2;
    __syncthreads();
    for (int off = 64; off > 0; off >>= 1) {
        if (tid < off) red[tid] += red[tid + off];
        __syncthreads();
    }
    float inv = 1.0f / red[0];
    __bf16* Ab = ADt + (size_t)b * TT * TT;
    Ab[(size_t)tid * TT + t] = (__bf16)(e0 * inv);
    Ab[(size_t)(tid + 128) * TT + t] = (__bf16)(e1 * inv);
    Ab[(size_t)(tid + 256) * TT + t] = (__bf16)(e2 * inv);
}

// ---- gemm3: C_Q[h][t] = sum_s Dt[h][s]*AQt[t][s] -> M4 rows 768.. ----
__global__ void gemm3_kernel(const __bf16* __restrict__ Dt, const __bf16* __restrict__ AQt,
                             __bf16* __restrict__ M4) {
    int b = blockIdx.z;
    int m0 = blockIdx.y * 16, n0 = blockIdx.x * 16;
    int lane = threadIdx.x;
    int mr = lane & 15, kq = (lane >> 4) * 8;
    const __bf16* A = Dt + (size_t)b * HH * TT;
    const __bf16* Bq = AQt + (size_t)b * TT * TT;
    f32x4 acc = {0.f, 0.f, 0.f, 0.f};
    for (int k0 = 0; k0 < TT; k0 += 32) {
        bf16x8 a = *(const bf16x8*)(A + (size_t)(m0 + mr) * TT + k0 + kq);
        bf16x8 bb = *(const bf16x8*)(Bq + (size_t)(n0 + mr) * TT + k0 + kq);
        acc = __builtin_amdgcn_mfma_f32_16x16x32_bf16(a, bb, acc, 0, 0, 0);
    }
    __bf16* Mb = M4 + (size_t)b * 1536 * TT;
    int col = n0 + (lane & 15);
    int row0 = m0 + (lane >> 4) * 4;
#pragma unroll
    for (int r = 0; r < 4; r++) Mb[(size_t)(768 + row0 + r) * TT + col] = (__bf16)acc[r];
}

// ---- gemm4: out[s][i] = sum_t ADt[s][t]*M4[i][t], i<1536 ----
__global__ void gemm4_kernel(const __bf16* __restrict__ ADt, const __bf16* __restrict__ M4,
                             float* __restrict__ out) {
    int b = blockIdx.z;
    int m0 = blockIdx.y * 16, n0 = blockIdx.x * 16;
    int lane = threadIdx.x;
    int mr = lane & 15, kq = (lane >> 4) * 8;
    const __bf16* A = ADt + (size_t)b * TT * TT;
    const __bf16* Bm = M4 + (size_t)b * 1536 * TT;
    f32x4 acc = {0.f, 0.f, 0.f, 0.f};
    for (int k0 = 0; k0 < TT; k0 += 32) {
        bf16x8 a = *(const bf16x8*)(A + (size_t)(m0 + mr) * TT + k0 + kq);
        bf16x8 bb = *(const bf16x8*)(Bm + (size_t)(n0 + mr) * TT + k0 + kq);
        acc = __builtin_amdgcn_mfma_f32_16x16x32_bf16(a, bb, acc, 0, 0, 0);
    }
    float* outb = out + (size_t)b * TT * 2304;
    int col = n0 + (lane & 15);
    int row0 = m0 + (lane >> 4) * 4;
#pragma unroll
    for (int r = 0; r < 4; r++) outb[(size_t)(row0 + r) * 2304 + col] = acc[r];
}

extern "C" void kernel_launch(void* const* d_in, const int* in_sizes, int n_in,
                              void* d_out, int out_size, void* d_ws, size_t ws_size,
                              hipStream_t stream) {
    const float* x = (const float*)d_in[0];
    const float* W = (const float*)d_in[1];
    const float* bias = (const float*)d_in[2];
    float* out = (float*)d_out;
    char* ws = (char*)d_ws;

    __bf16* Qhi = (__bf16*)(ws + 0);
    __bf16* Qlo = (__bf16*)(ws + 37748736);
    __bf16* M4 = (__bf16*)(ws + 75497472);
    __bf16* Dt = (__bf16*)(ws + 150994944);
    float* L = (float*)(ws + 188743680);
    // aliases (Qhi/Qlo dead after gemm2):
    __bf16* AQt = (__bf16*)(ws + 0);
    __bf16* ADt = (__bf16*)(ws + 37748736);
    // requires ws_size >= 226,492,416 bytes

    prep_kernel<<<dim3(24, 12, 64), dim3(32, 8), 0, stream>>>(x, Dt, out);
    gemm1_kernel<<<dim3(48, 24, 64), 64, 0, stream>>>(x, W, bias, Qhi, Qlo, M4);
    gemm2_kernel<<<dim3(24, 24, 64), 64, 0, stream>>>(Qhi, Qlo, x, L);
    softmax_col_kernel<<<dim3(384, 64), 128, 0, stream>>>(L, AQt);
    softmax_row_kernel<<<dim3(384, 64), 128, 0, stream>>>(L, ADt);
    gemm3_kernel<<<dim3(24, 48, 64), 64, 0, stream>>>(Dt, AQt, M4);
    gemm4_kernel<<<dim3(96, 24, 64), 64, 0, stream>>>(ADt, M4, out);
}

// Round 3
// 894.009 us; speedup vs baseline: 2.4950x; 2.4950x over previous
//
#include <hip/hip_runtime.h>

// CoAttention: B=64, H=768, T=384. out (64,384,2304) fp32.
// ws layout (bytes), aliasing (Qhi/Qlo dead after gemm2 -> AQt/ADt):
//   Qhi bf16 (64,384,768)  @ 0           37,748,736   later: AQt bf16 (64,384,384) @ 0
//   Qlo bf16 (64,384,768)  @ 37748736    37,748,736   later: ADt bf16 (64,384,384) @ 37748736
//   M4  bf16 (64,1536,384) @ 75497472    75,497,472   rows 0..767 Qact^T, 768..1535 C_Q
//   Dt  bf16 (64,768,384)  @ 150994944   37,748,736
//   L   f32  (64,384,384)  @ 188743680   37,748,736
// total 226,492,416 bytes (same as R1, known to fit)

typedef __bf16 bf16x8 __attribute__((ext_vector_type(8)));
typedef __bf16 bf16x4 __attribute__((ext_vector_type(4)));
typedef float  f32x4  __attribute__((ext_vector_type(4)));

#define HH 768
#define TT 384

__device__ inline void split8(const float* __restrict__ p, bf16x8& hi, bf16x8& lo) {
    float4 f0 = *(const float4*)p;
    float4 f1 = *(const float4*)(p + 4);
    float f[8] = {f0.x, f0.y, f0.z, f0.w, f1.x, f1.y, f1.z, f1.w};
#pragma unroll
    for (int i = 0; i < 8; i++) {
        __bf16 h = (__bf16)f[i];
        hi[i] = h;
        lo[i] = (__bf16)(f[i] - (float)h);
    }
}

// async global->LDS, 16B per lane; LDS side must be wave-uniform base + lane*16
__device__ inline void gload16(const void* g, void* l) {
    __builtin_amdgcn_global_load_lds(
        (const __attribute__((address_space(1))) unsigned int*)g,
        (__attribute__((address_space(3))) unsigned int*)l, 16, 0, 0);
}

// ---- prep: Dt[b][h][s] = bf16(D[b][s][h]);  out[b][s][1536+h] = D[b][s][h] ----
__global__ void prep_kernel(const float* __restrict__ x, __bf16* __restrict__ Dt,
                            float* __restrict__ out) {
    __shared__ float tile[32][33];
    int b = blockIdx.z;
    int h0 = blockIdx.x * 32, s0 = blockIdx.y * 32;
    int tx = threadIdx.x, ty = threadIdx.y;
    const float* src = x + ((size_t)b * HH + TT) * HH;  // D rows
    float* outb = out + (size_t)b * TT * 2304;
#pragma unroll
    for (int j = 0; j < 4; j++) {
        int s = s0 + ty + 8 * j, h = h0 + tx;
        float v = src[(size_t)s * HH + h];
        tile[ty + 8 * j][tx] = v;
        outb[(size_t)s * 2304 + 1536 + h] = v;
    }
    __syncthreads();
    __bf16* Dtb = Dt + (size_t)b * HH * TT;
#pragma unroll
    for (int j = 0; j < 4; j++) {
        int h = h0 + ty + 8 * j, s = s0 + tx;
        Dtb[(size_t)h * TT + s] = (__bf16)tile[tx][ty + 8 * j];
    }
}

// ---- gemm1: Qact = tanh(xQ @ W^T + b), split-precision (3 MFMA), 128x128 tile ----
__global__ __launch_bounds__(256) void gemm1_kernel(
    const float* __restrict__ x, const float* __restrict__ W,
    const float* __restrict__ bias, __bf16* __restrict__ Qhi,
    __bf16* __restrict__ Qlo, __bf16* __restrict__ M4) {
    __shared__ __bf16 Ah[128 * 32], Al[128 * 32], Bh[128 * 32], Bl[128 * 32];
    const int b = blockIdx.z;
    const int m_blk = blockIdx.y * 128, n_blk = blockIdx.x * 128;
    const int tid = threadIdx.x, lane = tid & 63, wave = tid >> 6;
    const int wm = wave >> 1, wn = wave & 1;
    const int r15 = lane & 15, quad = lane >> 4;
    const float* Abase = x + (size_t)b * HH * HH;  // Q rows
    f32x4 acc[4][4];
#pragma unroll
    for (int i = 0; i < 4; i++)
#pragma unroll
        for (int j = 0; j < 4; j++) acc[i][j] = (f32x4){0.f, 0.f, 0.f, 0.f};

    for (int k0 = 0; k0 < HH; k0 += 32) {
#pragma unroll
        for (int it = 0; it < 2; it++) {
            int c = it * 256 + tid;
            int r = c >> 2, q = c & 3;
            bf16x8 h, l;
            split8(Abase + (size_t)(m_blk + r) * HH + k0 + q * 8, h, l);
            *(bf16x8*)&Ah[c * 8] = h;
            *(bf16x8*)&Al[c * 8] = l;
            split8(W + (size_t)(n_blk + r) * HH + k0 + q * 8, h, l);
            *(bf16x8*)&Bh[c * 8] = h;
            *(bf16x8*)&Bl[c * 8] = l;
        }
        __syncthreads();
        bf16x8 ah[4], al[4], bh[4], bl[4];
#pragma unroll
        for (int i = 0; i < 4; i++) {
            int ra = (wm * 64 + i * 16 + r15) * 32 + quad * 8;
            ah[i] = *(const bf16x8*)&Ah[ra];
            al[i] = *(const bf16x8*)&Al[ra];
            int rb = (wn * 64 + i * 16 + r15) * 32 + quad * 8;
            bh[i] = *(const bf16x8*)&Bh[rb];
            bl[i] = *(const bf16x8*)&Bl[rb];
        }
#pragma unroll
        for (int i = 0; i < 4; i++)
#pragma unroll
            for (int j = 0; j < 4; j++) {
                acc[i][j] = __builtin_amdgcn_mfma_f32_16x16x32_bf16(ah[i], bh[j], acc[i][j], 0, 0, 0);
                acc[i][j] = __builtin_amdgcn_mfma_f32_16x16x32_bf16(ah[i], bl[j], acc[i][j], 0, 0, 0);
                acc[i][j] = __builtin_amdgcn_mfma_f32_16x16x32_bf16(al[i], bh[j], acc[i][j], 0, 0, 0);
            }
        __syncthreads();
    }
    __bf16* Qh = Qhi + (size_t)b * TT * HH;
    __bf16* Ql = Qlo + (size_t)b * TT * HH;
    __bf16* Mb = M4 + (size_t)b * 1536 * TT;
#pragma unroll
    for (int j = 0; j < 4; j++) {
        int col = n_blk + wn * 64 + j * 16 + r15;  // o
        float bv = bias[col];
#pragma unroll
        for (int i = 0; i < 4; i++) {
            int row0 = m_blk + wm * 64 + i * 16 + quad * 4;  // t
            bf16x4 mrow;
#pragma unroll
            for (int r = 0; r < 4; r++) {
                float v = tanhf(acc[i][j][r] + bv);
                __bf16 qh = (__bf16)v;
                Qh[(size_t)(row0 + r) * HH + col] = qh;
                Ql[(size_t)(row0 + r) * HH + col] = (__bf16)(v - (float)qh);
                mrow[r] = qh;
            }
            *(bf16x4*)&Mb[(size_t)col * TT + row0] = mrow;
        }
    }
}

// ---- gemm2: L[t][s] = sum_h Qact[t][h]*D[s][h], split-precision ----
__global__ __launch_bounds__(256) void gemm2_kernel(
    const __bf16* __restrict__ Qhi, const __bf16* __restrict__ Qlo,
    const float* __restrict__ x, float* __restrict__ L) {
    __shared__ __bf16 Ah[128 * 32], Al[128 * 32], Bh[128 * 32], Bl[128 * 32];
    const int b = blockIdx.z;
    const int m_blk = blockIdx.y * 128, n_blk = blockIdx.x * 128;
    const int tid = threadIdx.x, lane = tid & 63, wave = tid >> 6;
    const int wm = wave >> 1, wn = wave & 1;
    const int r15 = lane & 15, quad = lane >> 4;
    const __bf16* Qh = Qhi + (size_t)b * TT * HH;
    const __bf16* Ql = Qlo + (size_t)b * TT * HH;
    const float* Dbase = x + ((size_t)b * HH + TT) * HH;  // D rows
    f32x4 acc[4][4];
#pragma unroll
    for (int i = 0; i < 4; i++)
#pragma unroll
        for (int j = 0; j < 4; j++) acc[i][j] = (f32x4){0.f, 0.f, 0.f, 0.f};

    for (int k0 = 0; k0 < HH; k0 += 32) {
#pragma unroll
        for (int it = 0; it < 2; it++) {
            int c = it * 256 + tid;
            int r = c >> 2, q = c & 3;
            gload16(Qh + (size_t)(m_blk + r) * HH + k0 + q * 8, &Ah[c * 8]);
            gload16(Ql + (size_t)(m_blk + r) * HH + k0 + q * 8, &Al[c * 8]);
            bf16x8 h, l;
            split8(Dbase + (size_t)(n_blk + r) * HH + k0 + q * 8, h, l);
            *(bf16x8*)&Bh[c * 8] = h;
            *(bf16x8*)&Bl[c * 8] = l;
        }
        __syncthreads();
        bf16x8 ah[4], al[4], bh[4], bl[4];
#pragma unroll
        for (int i = 0; i < 4; i++) {
            int ra = (wm * 64 + i * 16 + r15) * 32 + quad * 8;
            ah[i] = *(const bf16x8*)&Ah[ra];
            al[i] = *(const bf16x8*)&Al[ra];
            int rb = (wn * 64 + i * 16 + r15) * 32 + quad * 8;
            bh[i] = *(const bf16x8*)&Bh[rb];
            bl[i] = *(const bf16x8*)&Bl[rb];
        }
#pragma unroll
        for (int i = 0; i < 4; i++)
#pragma unroll
            for (int j = 0; j < 4; j++) {
                acc[i][j] = __builtin_amdgcn_mfma_f32_16x16x32_bf16(ah[i], bh[j], acc[i][j], 0, 0, 0);
                acc[i][j] = __builtin_amdgcn_mfma_f32_16x16x32_bf16(ah[i], bl[j], acc[i][j], 0, 0, 0);
                acc[i][j] = __builtin_amdgcn_mfma_f32_16x16x32_bf16(al[i], bh[j], acc[i][j], 0, 0, 0);
            }
        __syncthreads();
    }
    float* Lb = L + (size_t)b * TT * TT;
#pragma unroll
    for (int j = 0; j < 4; j++) {
        int col = n_blk + wn * 64 + j * 16 + r15;  // s
#pragma unroll
        for (int i = 0; i < 4; i++) {
            int row0 = m_blk + wm * 64 + i * 16 + quad * 4;  // t
#pragma unroll
            for (int r = 0; r < 4; r++) Lb[(size_t)(row0 + r) * TT + col] = acc[i][j][r];
        }
    }
}

// ---- softmax over t (column) of L -> AQt[t][s] ----
__global__ void softmax_col_kernel(const float* __restrict__ L, __bf16* __restrict__ AQt) {
    int s = blockIdx.x, b = blockIdx.y;
    int tid = threadIdx.x;  // 128
    const float* Lb = L + (size_t)b * TT * TT;
    float v0 = Lb[(size_t)tid * TT + s];
    float v1 = Lb[(size_t)(tid + 128) * TT + s];
    float v2 = Lb[(size_t)(tid + 256) * TT + s];
    __shared__ float red[128];
    red[tid] = fmaxf(fmaxf(v0, v1), v2);
    __syncthreads();
    for (int off = 64; off > 0; off >>= 1) {
        if (tid < off) red[tid] = fmaxf(red[tid], red[tid + off]);
        __syncthreads();
    }
    float mx = red[0];
    __syncthreads();
    float e0 = __expf(v0 - mx), e1 = __expf(v1 - mx), e2 = __expf(v2 - mx);
    red[tid] = e0 + e1 + e2;
    __syncthreads();
    for (int off = 64; off > 0; off >>= 1) {
        if (tid < off) red[tid] += red[tid + off];
        __syncthreads();
    }
    float inv = 1.0f / red[0];
    __bf16* Ab = AQt + (size_t)b * TT * TT;
    Ab[(size_t)tid * TT + s] = (__bf16)(e0 * inv);
    Ab[(size_t)(tid + 128) * TT + s] = (__bf16)(e1 * inv);
    Ab[(size_t)(tid + 256) * TT + s] = (__bf16)(e2 * inv);
}

// ---- softmax over s (row) of L -> ADt[s][t] (transposed store) ----
__global__ void softmax_row_kernel(const float* __restrict__ L, __bf16* __restrict__ ADt) {
    int t = blockIdx.x, b = blockIdx.y;
    int tid = threadIdx.x;  // 128
    const float* Lb = L + (size_t)b * TT * TT + (size_t)t * TT;
    float v0 = Lb[tid], v1 = Lb[tid + 128], v2 = Lb[tid + 256];
    __shared__ float red[128];
    red[tid] = fmaxf(fmaxf(v0, v1), v2);
    __syncthreads();
    for (int off = 64; off > 0; off >>= 1) {
        if (tid < off) red[tid] = fmaxf(red[tid], red[tid + off]);
        __syncthreads();
    }
    float mx = red[0];
    __syncthreads();
    float e0 = __expf(v0 - mx), e1 = __expf(v1 - mx), e2 = __expf(v2 - mx);
    red[tid] = e0 + e1 + e2;
    __syncthreads();
    for (int off = 64; off > 0; off >>= 1) {
        if (tid < off) red[tid] += red[tid + off];
        __syncthreads();
    }
    float inv = 1.0f / red[0];
    __bf16* Ab = ADt + (size_t)b * TT * TT;
    Ab[(size_t)tid * TT + t] = (__bf16)(e0 * inv);
    Ab[(size_t)(tid + 128) * TT + t] = (__bf16)(e1 * inv);
    Ab[(size_t)(tid + 256) * TT + t] = (__bf16)(e2 * inv);
}

// ---- gemm3: C_Q[h][t] = sum_s Dt[h][s]*AQt[t][s] -> M4 rows 768..1535 ----
__global__ __launch_bounds__(256) void gemm3_kernel(
    const __bf16* __restrict__ Dt, const __bf16* __restrict__ AQt,
    __bf16* __restrict__ M4) {
    __shared__ __bf16 As[128 * 32], Bs[128 * 32];
    const int b = blockIdx.z;
    const int m_blk = blockIdx.y * 128, n_blk = blockIdx.x * 128;
    const int tid = threadIdx.x, lane = tid & 63, wave = tid >> 6;
    const int wm = wave >> 1, wn = wave & 1;
    const int r15 = lane & 15, quad = lane >> 4;
    const __bf16* Ab = Dt + (size_t)b * HH * TT;
    const __bf16* Bb = AQt + (size_t)b * TT * TT;
    f32x4 acc[4][4];
#pragma unroll
    for (int i = 0; i < 4; i++)
#pragma unroll
        for (int j = 0; j < 4; j++) acc[i][j] = (f32x4){0.f, 0.f, 0.f, 0.f};

    for (int k0 = 0; k0 < TT; k0 += 32) {
#pragma unroll
        for (int it = 0; it < 2; it++) {
            int c = it * 256 + tid;
            int r = c >> 2, q = c & 3;
            gload16(Ab + (size_t)(m_blk + r) * TT + k0 + q * 8, &As[c * 8]);
            gload16(Bb + (size_t)(n_blk + r) * TT + k0 + q * 8, &Bs[c * 8]);
        }
        __syncthreads();
        bf16x8 a[4], bf[4];
#pragma unroll
        for (int i = 0; i < 4; i++) {
            a[i] = *(const bf16x8*)&As[(wm * 64 + i * 16 + r15) * 32 + quad * 8];
            bf[i] = *(const bf16x8*)&Bs[(wn * 64 + i * 16 + r15) * 32 + quad * 8];
        }
#pragma unroll
        for (int i = 0; i < 4; i++)
#pragma unroll
            for (int j = 0; j < 4; j++)
                acc[i][j] = __builtin_amdgcn_mfma_f32_16x16x32_bf16(a[i], bf[j], acc[i][j], 0, 0, 0);
        __syncthreads();
    }
    __bf16* Mb = M4 + (size_t)b * 1536 * TT;
#pragma unroll
    for (int j = 0; j < 4; j++) {
        int col = n_blk + wn * 64 + j * 16 + r15;  // t
#pragma unroll
        for (int i = 0; i < 4; i++) {
            int row0 = m_blk + wm * 64 + i * 16 + quad * 4;  // h
#pragma unroll
            for (int r = 0; r < 4; r++)
                Mb[(size_t)(768 + row0 + r) * TT + col] = (__bf16)acc[i][j][r];
        }
    }
}

// ---- gemm4: out[s][i] = sum_t ADt[s][t]*M4[i][t], i<1536 ----
__global__ __launch_bounds__(256) void gemm4_kernel(
    const __bf16* __restrict__ ADt, const __bf16* __restrict__ M4,
    float* __restrict__ out) {
    __shared__ __bf16 As[128 * 32], Bs[128 * 32];
    const int b = blockIdx.z;
    const int m_blk = blockIdx.y * 128, n_blk = blockIdx.x * 128;
    const int tid = threadIdx.x, lane = tid & 63, wave = tid >> 6;
    const int wm = wave >> 1, wn = wave & 1;
    const int r15 = lane & 15, quad = lane >> 4;
    const __bf16* Ab = ADt + (size_t)b * TT * TT;
    const __bf16* Bb = M4 + (size_t)b * 1536 * TT;
    f32x4 acc[4][4];
#pragma unroll
    for (int i = 0; i < 4; i++)
#pragma unroll
        for (int j = 0; j < 4; j++) acc[i][j] = (f32x4){0.f, 0.f, 0.f, 0.f};

    for (int k0 = 0; k0 < TT; k0 += 32) {
#pragma unroll
        for (int it = 0; it < 2; it++) {
            int c = it * 256 + tid;
            int r = c >> 2, q = c & 3;
            gload16(Ab + (size_t)(m_blk + r) * TT + k0 + q * 8, &As[c * 8]);
            gload16(Bb + (size_t)(n_blk + r) * TT + k0 + q * 8, &Bs[c * 8]);
        }
        __syncthreads();
        bf16x8 a[4], bf[4];
#pragma unroll
        for (int i = 0; i < 4; i++) {
            a[i] = *(const bf16x8*)&As[(wm * 64 + i * 16 + r15) * 32 + quad * 8];
            bf[i] = *(const bf16x8*)&Bs[(wn * 64 + i * 16 + r15) * 32 + quad * 8];
        }
#pragma unroll
        for (int i = 0; i < 4; i++)
#pragma unroll
            for (int j = 0; j < 4; j++)
                acc[i][j] = __builtin_amdgcn_mfma_f32_16x16x32_bf16(a[i], bf[j], acc[i][j], 0, 0, 0);
        __syncthreads();
    }
    float* outb = out + (size_t)b * TT * 2304;
#pragma unroll
    for (int j = 0; j < 4; j++) {
        int col = n_blk + wn * 64 + j * 16 + r15;  // i
#pragma unroll
        for (int i = 0; i < 4; i++) {
            int row0 = m_blk + wm * 64 + i * 16 + quad * 4;  // s
#pragma unroll
            for (int r = 0; r < 4; r++)
                outb[(size_t)(row0 + r) * 2304 + col] = acc[i][j][r];
        }
    }
}

extern "C" void kernel_launch(void* const* d_in, const int* in_sizes, int n_in,
                              void* d_out, int out_size, void* d_ws, size_t ws_size,
                              hipStream_t stream) {
    const float* x = (const float*)d_in[0];
    const float* W = (const float*)d_in[1];
    const float* bias = (const float*)d_in[2];
    float* out = (float*)d_out;
    char* ws = (char*)d_ws;

    __bf16* Qhi = (__bf16*)(ws + 0);
    __bf16* Qlo = (__bf16*)(ws + 37748736);
    __bf16* M4 = (__bf16*)(ws + 75497472);
    __bf16* Dt = (__bf16*)(ws + 150994944);
    float* L = (float*)(ws + 188743680);
    // aliases (Qhi/Qlo dead after gemm2):
    __bf16* AQt = (__bf16*)(ws + 0);
    __bf16* ADt = (__bf16*)(ws + 37748736);

    prep_kernel<<<dim3(24, 12, 64), dim3(32, 8), 0, stream>>>(x, Dt, out);
    gemm1_kernel<<<dim3(6, 3, 64), 256, 0, stream>>>(x, W, bias, Qhi, Qlo, M4);
    gemm2_kernel<<<dim3(3, 3, 64), 256, 0, stream>>>(Qhi, Qlo, x, L);
    softmax_col_kernel<<<dim3(384, 64), 128, 0, stream>>>(L, AQt);
    softmax_row_kernel<<<dim3(384, 64), 128, 0, stream>>>(L, ADt);
    gemm3_kernel<<<dim3(3, 6, 64), 256, 0, stream>>>(Dt, AQt, M4);
    gemm4_kernel<<<dim3(12, 3, 64), 256, 0, stream>>>(ADt, M4, out);
}